// Round 4
// baseline (644.066 us; speedup 1.0000x reference)
//
#include <hip/hip_runtime.h>

using f32x4 = float    __attribute__((ext_vector_type(4)));
using f16x8 = _Float16 __attribute__((ext_vector_type(8)));

__device__ __forceinline__ void gload_lds16(const void* g, void* l) {
    __builtin_amdgcn_global_load_lds(
        (__attribute__((address_space(1))) void*)(void*)g,
        (__attribute__((address_space(3))) void*)l, 16, 0, 0);
}

// LDS k-seg swizzle (verified R3): writer lane (seg=lane&3, r16=lane>>2) pulls
// source k-seg ((seg-(r16>>1))&3); reader of k-seg `quad` for row lrow reads
// slot ((quad+(lrow>>1))&3). 2-way bank aliasing only (free).

// ---------------- fp32 -> fp16 elementwise convert (8 elems/thread) ---------
__global__ __launch_bounds__(256) void k_cvt_x(
    const float* __restrict__ in, _Float16* __restrict__ out) {
    int i = (blockIdx.x * 256 + threadIdx.x) * 8;
    f32x4 a = *(const f32x4*)(in + i);
    f32x4 b = *(const f32x4*)(in + i + 4);
    f16x8 o;
    #pragma unroll
    for (int j = 0; j < 4; ++j) { o[j] = (_Float16)a[j]; o[j + 4] = (_Float16)b[j]; }
    *(f16x8*)(out + i) = o;
}

// ---------------- fp32 in [R][C] -> fp16 out[c][r] (convert + transpose) ----
__global__ __launch_bounds__(256) void k_cvtT(
    const float* __restrict__ in, _Float16* __restrict__ out, int R, int C) {
    __shared__ _Float16 tile[32][33];
    int c0 = blockIdx.x * 32, r0 = blockIdx.y * 32;
    int tx = threadIdx.x & 31, ty = threadIdx.x >> 5;
    #pragma unroll
    for (int i = ty; i < 32; i += 8)
        tile[i][tx] = (_Float16)in[(size_t)(r0 + i) * C + c0 + tx];
    __syncthreads();
    #pragma unroll
    for (int i = ty; i < 32; i += 8)
        out[(size_t)(c0 + i) * R + r0 + tx] = tile[tx][i];
}

// ---------------- fp16 transpose: out[c][r] = in[r][c], in is [R][C] --------
__global__ __launch_bounds__(256) void k_transpose16(
    const _Float16* __restrict__ in, _Float16* __restrict__ out, int R, int C) {
    __shared__ _Float16 tile[32][33];
    int c0 = blockIdx.x * 32, r0 = blockIdx.y * 32;
    int tx = threadIdx.x & 31, ty = threadIdx.x >> 5;
    #pragma unroll
    for (int i = ty; i < 32; i += 8)
        tile[i][tx] = in[(size_t)(r0 + i) * C + c0 + tx];
    __syncthreads();
    #pragma unroll
    for (int i = ty; i < 32; i += 8)
        out[(size_t)(c0 + i) * R + r0 + tx] = tile[tx][i];
}

// ---------------- A-resident GEMM: C = A @ Bt^T, K<=512 --------------------
// BM=64 rows of A staged ONCE into LDS (64KB); Bt streamed 32-k at a time.
// 256 thr / 4 waves; each wave owns all 64 rows x 64 cols. 80KB LDS = 2 blk/CU.
// OM: 0 = fp32 store, 1 = fp16 store
template<int OM>
__global__ __launch_bounds__(256, 2) void k_gemm_ares(
    const _Float16* __restrict__ A, int lda,
    const _Float16* __restrict__ Bt, int ldb,
    void* __restrict__ Cp, int ldc, int K) {
    __shared__ _Float16 Ts[64 * 512];   // chunk ci = cb*4+rb: [16 rows][32 k]
    __shared__ _Float16 Bs[256 * 32];
    const int row0 = blockIdx.y * 64, col0 = blockIdx.x * 256;
    const int tid = threadIdx.x, w = tid >> 6, lane = tid & 63;
    const int lrow = lane & 15, quad = lane >> 4;
    const int r16 = lane >> 2;
    const int kc = (((lane & 3) - ((lane >> 3) & 3)) & 3) * 8;
    const int sq = ((quad + ((lrow >> 1) & 3)) & 3) * 8;
    const int nks = K >> 5;             // 16 for K=512
    // stage full A tile (rows row0..row0+64, all K)
    for (int ci = w; ci < nks * 4; ci += 4) {
        int rb = ci & 3, cb = ci >> 2;
        gload_lds16(A + (size_t)(row0 + rb * 16 + r16) * lda + cb * 32 + kc,
                    Ts + ci * 512 + lane * 8);
    }
    f32x4 acc[4][4] = {};
    for (int ks = 0; ks < nks; ++ks) {
        for (int ci = w; ci < 16; ci += 4)
            gload_lds16(Bt + (size_t)(col0 + ci * 16 + r16) * ldb + ks * 32 + kc,
                        Bs + ci * 512 + lane * 8);
        __syncthreads();
        f16x8 af[4], bf[4];
        #pragma unroll
        for (int i = 0; i < 4; ++i)
            af[i] = *(const f16x8*)(Ts + (ks * 4 + i) * 512 + lrow * 32 + sq);
        #pragma unroll
        for (int i = 0; i < 4; ++i)
            bf[i] = *(const f16x8*)(Bs + (w * 4 + i) * 512 + lrow * 32 + sq);
        #pragma unroll
        for (int mi = 0; mi < 4; ++mi)
            #pragma unroll
            for (int ni = 0; ni < 4; ++ni)
                acc[mi][ni] = __builtin_amdgcn_mfma_f32_16x16x32_f16(
                    af[mi], bf[ni], acc[mi][ni], 0, 0, 0);
        __syncthreads();
    }
    #pragma unroll
    for (int mi = 0; mi < 4; ++mi) {
        #pragma unroll
        for (int ni = 0; ni < 4; ++ni) {
            int col = col0 + w * 64 + ni * 16 + lrow;
            #pragma unroll
            for (int r = 0; r < 4; ++r) {
                int row = row0 + mi * 16 + quad * 4 + r;
                float v = acc[mi][ni][r];
                if constexpr (OM == 1)
                    ((_Float16*)Cp)[(size_t)row * ldc + col] = (_Float16)v;
                else
                    ((float*)Cp)[(size_t)row * ldc + col] = v;
            }
        }
    }
}

// ---------------- wide GEMM3: part[z] = P[:, zchunk] @ Wh[zchunk, :] --------
// BM=128, BN=512 (x=1: P fetched exactly once), BK=32, split-K z=4 (2048 each)
// 512 thr / 8 waves (2x4): wave = 64 rows x 128 cols; 12 reads / 32 MFMA.
__global__ __launch_bounds__(512, 2) void k_gemm_wide(
    const _Float16* __restrict__ A,      // P [8192][8192]
    const _Float16* __restrict__ Bt,     // WhT [512][8192]
    float* __restrict__ Cp) {            // partials [4][8192][512]
    __shared__ _Float16 As[128 * 32];
    __shared__ _Float16 Bs[512 * 32];
    const int row0 = blockIdx.y * 128;
    const size_t zoff = (size_t)blockIdx.z * 2048;
    Cp += (size_t)blockIdx.z * ((size_t)8192 * 512);
    const int tid = threadIdx.x, w = tid >> 6, lane = tid & 63;
    const int wm = w >> 2, wn = w & 3;
    const int lrow = lane & 15, quad = lane >> 4;
    const int r16 = lane >> 2;
    const int kc = (((lane & 3) - ((lane >> 3) & 3)) & 3) * 8;
    const int sq = ((quad + ((lrow >> 1) & 3)) & 3) * 8;
    f32x4 acc[4][8] = {};
    for (int k0 = 0; k0 < 2048; k0 += 32) {
        #pragma unroll
        for (int i = 0; i < 5; ++i) {
            int c = w + i * 8;           // 40 chunks / 8 waves
            if (c < 8) {
                gload_lds16(A + (size_t)(row0 + c * 16 + r16) * 8192 + zoff + k0 + kc,
                            As + c * 512 + lane * 8);
            } else {
                int c2 = c - 8;
                gload_lds16(Bt + (size_t)(c2 * 16 + r16) * 8192 + zoff + k0 + kc,
                            Bs + c2 * 512 + lane * 8);
            }
        }
        __syncthreads();
        f16x8 af[4], bf[8];
        #pragma unroll
        for (int i = 0; i < 4; ++i)
            af[i] = *(const f16x8*)(As + (wm * 4 + i) * 512 + lrow * 32 + sq);
        #pragma unroll
        for (int i = 0; i < 8; ++i)
            bf[i] = *(const f16x8*)(Bs + (wn * 8 + i) * 512 + lrow * 32 + sq);
        #pragma unroll
        for (int mi = 0; mi < 4; ++mi)
            #pragma unroll
            for (int ni = 0; ni < 8; ++ni)
                acc[mi][ni] = __builtin_amdgcn_mfma_f32_16x16x32_f16(
                    af[mi], bf[ni], acc[mi][ni], 0, 0, 0);
        __syncthreads();
    }
    #pragma unroll
    for (int mi = 0; mi < 4; ++mi) {
        #pragma unroll
        for (int ni = 0; ni < 8; ++ni) {
            int col = wn * 128 + ni * 16 + lrow;
            #pragma unroll
            for (int r = 0; r < 4; ++r) {
                int row = row0 + wm * 64 + mi * 16 + quad * 4 + r;
                Cp[(size_t)row * 512 + col] = acc[mi][ni][r];
            }
        }
    }
}

// ---------------- split WhWs -> Wh(fp16), T = tanh(Wh+Ws+bias) (fp16) -------
__global__ __launch_bounds__(256) void k_tanh_split(
    const float* __restrict__ WhWs, _Float16* __restrict__ T,
    _Float16* __restrict__ Wh,
    const float* __restrict__ aw, const float* __restrict__ ab) {
    int i = blockIdx.x * 256 + threadIdx.x;      // over 8192*512
    float bias = aw[0] + ab[0];
    int row = i >> 9, col = i & 511;
    float wh  = WhWs[(size_t)row * 1024 + col];
    float wsv = WhWs[(size_t)row * 1024 + 512 + col];
    Wh[i] = (_Float16)wh;
    T[i]  = (_Float16)tanhf(wh + wsv + bias);
}

// ---------------- row softmax in place: S fp16 -> P fp16 --------------------
__global__ __launch_bounds__(256) void k_softmax_rows(
    _Float16* __restrict__ S, int N) {
    const int row = blockIdx.x;
    _Float16* prow = S + (size_t)row * N;
    const int t = threadIdx.x;
    float v[32];
    #pragma unroll
    for (int it = 0; it < 4; ++it) {
        f16x8 h = *(const f16x8*)(prow + (it * 256 + t) * 8);
        #pragma unroll
        for (int j = 0; j < 8; ++j) v[it * 8 + j] = (float)h[j];
    }
    float m = v[0];
    #pragma unroll
    for (int j = 1; j < 32; ++j) m = fmaxf(m, v[j]);
    #pragma unroll
    for (int off = 32; off > 0; off >>= 1) m = fmaxf(m, __shfl_xor(m, off));
    __shared__ float red[8];
    const int wid = t >> 6, lane = t & 63;
    if (lane == 0) red[wid] = m;
    __syncthreads();
    m = fmaxf(fmaxf(red[0], red[1]), fmaxf(red[2], red[3]));
    float l = 0.f;
    #pragma unroll
    for (int j = 0; j < 32; ++j) l += __expf(v[j] - m);
    #pragma unroll
    for (int off = 32; off > 0; off >>= 1) l += __shfl_xor(l, off);
    if (lane == 0) red[4 + wid] = l;
    __syncthreads();
    float rl = 1.f / (red[4] + red[5] + red[6] + red[7]);
    #pragma unroll
    for (int it = 0; it < 4; ++it) {
        f16x8 pk;
        #pragma unroll
        for (int j = 0; j < 8; ++j)
            pk[j] = (_Float16)(__expf(v[it * 8 + j] - m) * rl);
        *(f16x8*)(prow + (it * 256 + t) * 8) = pk;
    }
}

// ------- fused: outf = sum(part[0..3]) + X, plus column sum/sumsq atomics ---
__global__ __launch_bounds__(256) void k_reduce_stats(
    const float* __restrict__ part, const float* __restrict__ X,
    float* __restrict__ outf, float* __restrict__ cs, float* __restrict__ cq) {
    const int t = threadIdx.x;
    const int r0 = blockIdx.x * 128;
    constexpr size_t PS = (size_t)8192 * 512;
    float s0 = 0, q0 = 0, s1 = 0, q1 = 0;
    for (int r = 0; r < 128; ++r) {
        size_t base = (size_t)(r0 + r) * 512;
        float a = part[base + t] + part[PS + base + t]
                + part[2 * PS + base + t] + part[3 * PS + base + t] + X[base + t];
        float b = part[base + t + 256] + part[PS + base + t + 256]
                + part[2 * PS + base + t + 256] + part[3 * PS + base + t + 256]
                + X[base + t + 256];
        outf[base + t] = a;       outf[base + t + 256] = b;
        s0 += a; q0 += a * a; s1 += b; q1 += b * b;
    }
    atomicAdd(&cs[t], s0);       atomicAdd(&cq[t], q0);
    atomicAdd(&cs[t + 256], s1); atomicAdd(&cq[t + 256], q1);
}

// ---------------- batchnorm (no affine) + leaky relu -> fp32 ----------------
__global__ __launch_bounds__(256) void k_bn_lrelu(
    const float* __restrict__ outf, const float* __restrict__ colsum,
    const float* __restrict__ colsq, float* __restrict__ out) {
    int i = blockIdx.x * 256 + threadIdx.x;
    int c = i & 511;
    constexpr float rN = 1.f / 8192.f;
    float mean = colsum[c] * rN;
    float var  = colsq[c] * rN - mean * mean;
    float y = (outf[i] - mean) * rsqrtf(var + 1e-5f);
    y = (y >= 0.f) ? y : 0.01f * y;
    out[i] = y;
}

extern "C" void kernel_launch(void* const* d_in, const int* in_sizes, int n_in,
                              void* d_out, int out_size, void* d_ws, size_t ws_size,
                              hipStream_t stream) {
    const float* X  = (const float*)d_in[0];  // [8192,512] fp32
    // d_in[1] = adj, unused
    const float* W  = (const float*)d_in[2];  // [512,1024] fp32
    const float* aw = (const float*)d_in[3];
    const float* ab = (const float*)d_in[4];
    float* out = (float*)d_out;               // [8192,512] fp32

    char* ws = (char*)d_ws;
    _Float16* Xh   = (_Float16*)(ws + 0x0);          //   8 MB [8192,512]
    _Float16* Wt   = (_Float16*)(ws + 0x800000);     //   1 MB W^T [1024,512]
    float*    WhWs = (float*)   (ws + 0x900000);     //  32 MB [8192,1024] fp32
    _Float16* T    = (_Float16*)(ws + 0x2900000);    //   8 MB [8192,512]
    _Float16* Whh  = (_Float16*)(ws + 0x3100000);    //   8 MB [8192,512]
    _Float16* WhT  = (_Float16*)(ws + 0x3900000);    //   8 MB [512,8192]
    _Float16* S    = (_Float16*)(ws + 0x4100000);    // 128 MB [8192,8192] fp16
    float*    outf = (float*)   (ws + 0xC100000);    //  16 MB [8192,512] fp32
    float*    part = (float*)   (ws + 0xD100000);    //  64 MB 4x[8192,512] fp32
    float*    cs   = (float*)   (ws + 0x11100000);   //   2 KB
    float*    cq   = (float*)   (ws + 0x11100800);   //   2 KB

    // stats accumulators zeroed up-front (independent of everything else)
    hipMemsetAsync(cs, 0, 4096, stream);
    // 0. Xh = fp16(X);  Wt = fp16(W^T)
    k_cvt_x<<<dim3((8192 * 512) / 2048), 256, 0, stream>>>(X, Xh);
    k_cvtT<<<dim3(1024 / 32, 512 / 32), 256, 0, stream>>>(W, Wt, 512, 1024);
    // 1. WhWs = Xh @ W  (fp32)  M=8192 N=1024 K=512
    k_gemm_ares<0><<<dim3(1024 / 256, 8192 / 64), 256, 0, stream>>>(
        Xh, 512, Wt, 512, WhWs, 1024, 512);
    // 2. Whh (fp16) and T = tanh(Wh + Ws + bias) (fp16)
    k_tanh_split<<<dim3((8192 * 512) / 256), 256, 0, stream>>>(WhWs, T, Whh, aw, ab);
    // 3. WhT = Whh^T
    k_transpose16<<<dim3(512 / 32, 8192 / 32), 256, 0, stream>>>(Whh, WhT, 8192, 512);
    // 4. S = T @ Whh^T  (fp16)  M=8192 N=8192 K=512
    k_gemm_ares<1><<<dim3(8192 / 256, 8192 / 64), 256, 0, stream>>>(
        T, 512, Whh, 512, S, 8192, 512);
    // 5. row softmax in place: S -> P (fp16)
    k_softmax_rows<<<dim3(8192), 256, 0, stream>>>(S, 8192);
    // 6. part[z] = P[:, z-chunk] @ Wh[z-chunk, :]  (BN=512, P read once)
    k_gemm_wide<<<dim3(1, 64, 4), 512, 0, stream>>>(S, WhT, part);
    // 7. outf = sum(part) + X, with fused column stats
    k_reduce_stats<<<dim3(64), 256, 0, stream>>>(part, X, outf, cs, cq);
    // 8. batchnorm + leaky relu
    k_bn_lrelu<<<dim3((8192 * 512) / 256), 256, 0, stream>>>(outf, cs, cq, out);
}

// Round 6
// 565.839 us; speedup vs baseline: 1.1382x; 1.1382x over previous
//
#include <hip/hip_runtime.h>

using f32x4 = float    __attribute__((ext_vector_type(4)));
using f16x8 = _Float16 __attribute__((ext_vector_type(8)));

__device__ __forceinline__ void gload_lds16(const void* g, void* l) {
    __builtin_amdgcn_global_load_lds(
        (__attribute__((address_space(1))) void*)(void*)g,
        (__attribute__((address_space(3))) void*)l, 16, 0, 0);
}

// LDS k-seg swizzle (validated R3): staging lane (seg=lane&3, row r16=lane>>2)
// pulls source k-seg ((seg-(r16>>1))&3); reader of k-seg `quad` for row lrow
// reads slot ((quad+(lrow>>1))&3). Bank aliasing collapses 8-way -> 2-way (free).

// ---------------- fp32 -> fp16 elementwise convert (8 elems/thread) ---------
__global__ __launch_bounds__(256) void k_cvt_x(
    const float* __restrict__ in, _Float16* __restrict__ out) {
    int i = (blockIdx.x * 256 + threadIdx.x) * 8;
    f32x4 a = *(const f32x4*)(in + i);
    f32x4 b = *(const f32x4*)(in + i + 4);
    f16x8 o;
    #pragma unroll
    for (int j = 0; j < 4; ++j) { o[j] = (_Float16)a[j]; o[j + 4] = (_Float16)b[j]; }
    *(f16x8*)(out + i) = o;
}

// ---------------- fp32 in [R][C] -> fp16 out[c][r] (convert + transpose) ----
__global__ __launch_bounds__(256) void k_cvtT(
    const float* __restrict__ in, _Float16* __restrict__ out, int R, int C) {
    __shared__ _Float16 tile[32][33];
    int c0 = blockIdx.x * 32, r0 = blockIdx.y * 32;
    int tx = threadIdx.x & 31, ty = threadIdx.x >> 5;
    #pragma unroll
    for (int i = ty; i < 32; i += 8)
        tile[i][tx] = (_Float16)in[(size_t)(r0 + i) * C + c0 + tx];
    __syncthreads();
    #pragma unroll
    for (int i = ty; i < 32; i += 8)
        out[(size_t)(c0 + i) * R + r0 + tx] = tile[tx][i];
}

// ---------------- fp16 transpose: out[c][r] = in[r][c], in is [R][C] --------
__global__ __launch_bounds__(256) void k_transpose16(
    const _Float16* __restrict__ in, _Float16* __restrict__ out, int R, int C) {
    __shared__ _Float16 tile[32][33];
    int c0 = blockIdx.x * 32, r0 = blockIdx.y * 32;
    int tx = threadIdx.x & 31, ty = threadIdx.x >> 5;
    #pragma unroll
    for (int i = ty; i < 32; i += 8)
        tile[i][tx] = in[(size_t)(r0 + i) * C + c0 + tx];
    __syncthreads();
    #pragma unroll
    for (int i = ty; i < 32; i += 8)
        out[(size_t)(c0 + i) * R + r0 + tx] = tile[tx][i];
}

// ---------------- m97-style fp16 GEMM, C = A @ Bt^T (R3-validated) ----------
// A: [M,K] fp16 row-major, Bt: [N,K] fp16 row-major. BM=128 fixed.
// OM: 0 = fp32 store, 1 = fp16 store
template<int OM, int BN>
__global__ __launch_bounds__(256, 2) void k_gemm_bt(
    const _Float16* __restrict__ A, int lda,
    const _Float16* __restrict__ Bt, int ldb,
    void* __restrict__ Cp, int ldc, int K) {
    constexpr int BM  = 128;
    constexpr int NI  = BN / 32;
    constexpr int NCH = (BM + BN) / 16;
    __shared__ _Float16 As[BM * 32];
    __shared__ _Float16 Bs[BN * 32];
    const int row0 = blockIdx.y * BM, col0 = blockIdx.x * BN;
    const int tid = threadIdx.x, w = tid >> 6, lane = tid & 63;
    const int wm = w >> 1, wn = w & 1;
    const int lrow = lane & 15, quad = lane >> 4;
    const int r16 = lane >> 2;
    const int kc  = (((lane & 3) - ((lane >> 3) & 3)) & 3) * 8;
    const int sq  = ((quad + ((lrow >> 1) & 3)) & 3) * 8;
    f32x4 acc[4][NI] = {};

    for (int k0 = 0; k0 < K; k0 += 32) {
        #pragma unroll
        for (int i = 0; i < NCH / 4; ++i) {
            int c = w + i * 4;
            if (c < BM / 16) {
                gload_lds16(A + (size_t)(row0 + c * 16 + r16) * lda + (k0 + kc),
                            As + c * 512);
            } else {
                int c2 = c - BM / 16;
                gload_lds16(Bt + (size_t)(col0 + c2 * 16 + r16) * ldb + (k0 + kc),
                            Bs + c2 * 512);
            }
        }
        __syncthreads();
        f16x8 af[4], bfr[NI];
        #pragma unroll
        for (int i = 0; i < 4; ++i)
            af[i] = *(const f16x8*)(As + (wm * 64 + i * 16 + lrow) * 32 + sq);
        #pragma unroll
        for (int i = 0; i < NI; ++i)
            bfr[i] = *(const f16x8*)(Bs + (wn * (BN / 2) + i * 16 + lrow) * 32 + sq);
        #pragma unroll
        for (int mi = 0; mi < 4; ++mi)
            #pragma unroll
            for (int ni = 0; ni < NI; ++ni)
                acc[mi][ni] = __builtin_amdgcn_mfma_f32_16x16x32_f16(
                    af[mi], bfr[ni], acc[mi][ni], 0, 0, 0);
        __syncthreads();
    }
    #pragma unroll
    for (int mi = 0; mi < 4; ++mi) {
        #pragma unroll
        for (int ni = 0; ni < NI; ++ni) {
            int col = col0 + wn * (BN / 2) + ni * 16 + lrow;
            #pragma unroll
            for (int r = 0; r < 4; ++r) {
                int row = row0 + wm * 64 + mi * 16 + quad * 4 + r;
                float v = acc[mi][ni][r];
                if constexpr (OM == 1)
                    ((_Float16*)Cp)[(size_t)row * ldc + col] = (_Float16)v;
                else
                    ((float*)Cp)[(size_t)row * ldc + col] = v;
            }
        }
    }
}

// ------- GEMM3: part[z] = P[:, zchunk] @ Wh[zchunk, :]  (split-K z=4) -------
// BM=128, BN=256, 512 thr / 8 waves (wm 0..1, wn 0..3), grid (2,64,4)=512
// blocks -> 2 blocks/CU, 16 waves/CU. Per-wave K-step: 3 gloads, 8 ds_read,
// 16 MFMA (m97 shape). S over-fetch 2x only.
__global__ __launch_bounds__(512, 4) void k_gemm3(
    const _Float16* __restrict__ A,      // P [8192][8192]
    const _Float16* __restrict__ Bt,     // WhT [512][8192]
    float* __restrict__ Cp) {            // partials [4][8192][512]
    __shared__ _Float16 As[128 * 32];
    __shared__ _Float16 Bs[256 * 32];
    const int row0 = blockIdx.y * 128, col0 = blockIdx.x * 256;
    const size_t zoff = (size_t)blockIdx.z * 2048;
    Cp += (size_t)blockIdx.z * ((size_t)8192 * 512);
    const int tid = threadIdx.x, w = tid >> 6, lane = tid & 63;
    const int wm = w >> 2, wn = w & 3;
    const int lrow = lane & 15, quad = lane >> 4;
    const int r16 = lane >> 2;
    const int kc = (((lane & 3) - ((lane >> 3) & 3)) & 3) * 8;
    const int sq = ((quad + ((lrow >> 1) & 3)) & 3) * 8;
    f32x4 acc[4][4] = {};
    for (int k0 = 0; k0 < 2048; k0 += 32) {
        #pragma unroll
        for (int i = 0; i < 3; ++i) {
            int c = w + i * 8;           // 24 chunks / 8 waves
            if (c < 8) {
                gload_lds16(A + (size_t)(row0 + c * 16 + r16) * 8192 + zoff + k0 + kc,
                            As + c * 512);
            } else {
                int c2 = c - 8;
                gload_lds16(Bt + (size_t)(col0 + c2 * 16 + r16) * 8192 + zoff + k0 + kc,
                            Bs + c2 * 512);
            }
        }
        __syncthreads();
        f16x8 af[4], bf[4];
        #pragma unroll
        for (int i = 0; i < 4; ++i)
            af[i] = *(const f16x8*)(As + (wm * 64 + i * 16 + lrow) * 32 + sq);
        #pragma unroll
        for (int i = 0; i < 4; ++i)
            bf[i] = *(const f16x8*)(Bs + (wn * 64 + i * 16 + lrow) * 32 + sq);
        #pragma unroll
        for (int mi = 0; mi < 4; ++mi)
            #pragma unroll
            for (int ni = 0; ni < 4; ++ni)
                acc[mi][ni] = __builtin_amdgcn_mfma_f32_16x16x32_f16(
                    af[mi], bf[ni], acc[mi][ni], 0, 0, 0);
        __syncthreads();
    }
    #pragma unroll
    for (int mi = 0; mi < 4; ++mi) {
        #pragma unroll
        for (int ni = 0; ni < 4; ++ni) {
            int col = col0 + wn * 64 + ni * 16 + lrow;
            #pragma unroll
            for (int r = 0; r < 4; ++r) {
                int row = row0 + wm * 64 + mi * 16 + quad * 4 + r;
                Cp[(size_t)row * 512 + col] = acc[mi][ni][r];
            }
        }
    }
}

// ---------------- split WhWs -> Wh(fp16), T = tanh(Wh+Ws+bias) (fp16) -------
__global__ __launch_bounds__(256) void k_tanh_split(
    const float* __restrict__ WhWs, _Float16* __restrict__ T,
    _Float16* __restrict__ Wh,
    const float* __restrict__ aw, const float* __restrict__ ab) {
    int i = blockIdx.x * 256 + threadIdx.x;      // over 8192*512
    float bias = aw[0] + ab[0];
    int row = i >> 9, col = i & 511;
    float wh  = WhWs[(size_t)row * 1024 + col];
    float wsv = WhWs[(size_t)row * 1024 + 512 + col];
    Wh[i] = (_Float16)wh;
    T[i]  = (_Float16)tanhf(wh + wsv + bias);
}

// ---------------- row softmax in place: S fp16 -> P fp16 --------------------
__global__ __launch_bounds__(256) void k_softmax_rows(
    _Float16* __restrict__ S, int N) {
    const int row = blockIdx.x;
    _Float16* prow = S + (size_t)row * N;
    const int t = threadIdx.x;
    float v[32];
    #pragma unroll
    for (int it = 0; it < 4; ++it) {
        f16x8 h = *(const f16x8*)(prow + (it * 256 + t) * 8);
        #pragma unroll
        for (int j = 0; j < 8; ++j) v[it * 8 + j] = (float)h[j];
    }
    float m = v[0];
    #pragma unroll
    for (int j = 1; j < 32; ++j) m = fmaxf(m, v[j]);
    #pragma unroll
    for (int off = 32; off > 0; off >>= 1) m = fmaxf(m, __shfl_xor(m, off));
    __shared__ float red[8];
    const int wid = t >> 6, lane = t & 63;
    if (lane == 0) red[wid] = m;
    __syncthreads();
    m = fmaxf(fmaxf(red[0], red[1]), fmaxf(red[2], red[3]));
    float l = 0.f;
    #pragma unroll
    for (int j = 0; j < 32; ++j) l += __expf(v[j] - m);
    #pragma unroll
    for (int off = 32; off > 0; off >>= 1) l += __shfl_xor(l, off);
    if (lane == 0) red[4 + wid] = l;
    __syncthreads();
    float rl = 1.f / (red[4] + red[5] + red[6] + red[7]);
    #pragma unroll
    for (int it = 0; it < 4; ++it) {
        f16x8 pk;
        #pragma unroll
        for (int j = 0; j < 8; ++j)
            pk[j] = (_Float16)(__expf(v[it * 8 + j] - m) * rl);
        *(f16x8*)(prow + (it * 256 + t) * 8) = pk;
    }
}

// ------- fused: outf = sum(part[0..3]) + X, plus column sum/sumsq atomics ---
// 256 blocks x 32 rows: full-GPU parallelism (R4's 64-block version was 4x
// under-parallel and cost ~60us).
__global__ __launch_bounds__(256) void k_reduce_stats(
    const float* __restrict__ part, const float* __restrict__ X,
    float* __restrict__ outf, float* __restrict__ cs, float* __restrict__ cq) {
    const int t = threadIdx.x;
    const int r0 = blockIdx.x * 32;
    constexpr size_t PS = (size_t)8192 * 512;
    float s0 = 0, q0 = 0, s1 = 0, q1 = 0;
    for (int r = 0; r < 32; ++r) {
        size_t base = (size_t)(r0 + r) * 512;
        float a = part[base + t] + part[PS + base + t]
                + part[2 * PS + base + t] + part[3 * PS + base + t] + X[base + t];
        float b = part[base + t + 256] + part[PS + base + t + 256]
                + part[2 * PS + base + t + 256] + part[3 * PS + base + t + 256]
                + X[base + t + 256];
        outf[base + t] = a;       outf[base + t + 256] = b;
        s0 += a; q0 += a * a; s1 += b; q1 += b * b;
    }
    atomicAdd(&cs[t], s0);       atomicAdd(&cq[t], q0);
    atomicAdd(&cs[t + 256], s1); atomicAdd(&cq[t + 256], q1);
}

// ---------------- batchnorm (no affine) + leaky relu -> fp32 ----------------
__global__ __launch_bounds__(256) void k_bn_lrelu(
    const float* __restrict__ outf, const float* __restrict__ colsum,
    const float* __restrict__ colsq, float* __restrict__ out) {
    int i = blockIdx.x * 256 + threadIdx.x;
    int c = i & 511;
    constexpr float rN = 1.f / 8192.f;
    float mean = colsum[c] * rN;
    float var  = colsq[c] * rN - mean * mean;
    float y = (outf[i] - mean) * rsqrtf(var + 1e-5f);
    y = (y >= 0.f) ? y : 0.01f * y;
    out[i] = y;
}

extern "C" void kernel_launch(void* const* d_in, const int* in_sizes, int n_in,
                              void* d_out, int out_size, void* d_ws, size_t ws_size,
                              hipStream_t stream) {
    const float* X  = (const float*)d_in[0];  // [8192,512] fp32
    // d_in[1] = adj, unused
    const float* W  = (const float*)d_in[2];  // [512,1024] fp32
    const float* aw = (const float*)d_in[3];
    const float* ab = (const float*)d_in[4];
    float* out = (float*)d_out;               // [8192,512] fp32

    char* ws = (char*)d_ws;
    _Float16* Xh   = (_Float16*)(ws + 0x0);          //   8 MB [8192,512]
    _Float16* Wt   = (_Float16*)(ws + 0x800000);     //   1 MB W^T [1024,512]
    float*    WhWs = (float*)   (ws + 0x900000);     //  32 MB [8192,1024] fp32
    _Float16* T    = (_Float16*)(ws + 0x2900000);    //   8 MB [8192,512]
    _Float16* Whh  = (_Float16*)(ws + 0x3100000);    //   8 MB [8192,512]
    _Float16* WhT  = (_Float16*)(ws + 0x3900000);    //   8 MB [512,8192]
    _Float16* S    = (_Float16*)(ws + 0x4100000);    // 128 MB [8192,8192] fp16
    float*    outf = (float*)   (ws + 0xC100000);    //  16 MB [8192,512] fp32
    float*    part = (float*)   (ws + 0xD100000);    //  64 MB 4x[8192,512] fp32
    float*    cs   = (float*)   (ws + 0x11100000);   //   2 KB
    float*    cq   = (float*)   (ws + 0x11100800);   //   2 KB

    // stats accumulators zeroed up-front
    hipMemsetAsync(cs, 0, 4096, stream);
    // 0. Xh = fp16(X);  Wt = fp16(W^T)
    k_cvt_x<<<dim3((8192 * 512) / 2048), 256, 0, stream>>>(X, Xh);
    k_cvtT<<<dim3(1024 / 32, 512 / 32), 256, 0, stream>>>(W, Wt, 512, 1024);
    // 1. WhWs = Xh @ W  (fp32)  M=8192 N=1024 K=512
    k_gemm_bt<0, 128><<<dim3(1024 / 128, 8192 / 128), 256, 0, stream>>>(
        Xh, 512, Wt, 512, WhWs, 1024, 512);
    // 2. Whh (fp16) and T = tanh(Wh + Ws + bias) (fp16)
    k_tanh_split<<<dim3((8192 * 512) / 256), 256, 0, stream>>>(WhWs, T, Whh, aw, ab);
    // 3. WhT = Whh^T
    k_transpose16<<<dim3(512 / 32, 8192 / 32), 256, 0, stream>>>(Whh, WhT, 8192, 512);
    // 4. S = T @ Whh^T  (fp16)  M=8192 N=8192 K=512
    k_gemm_bt<1, 128><<<dim3(8192 / 128, 8192 / 128), 256, 0, stream>>>(
        T, 512, Whh, 512, S, 8192, 512);
    // 5. row softmax in place: S -> P (fp16)
    k_softmax_rows<<<dim3(8192), 256, 0, stream>>>(S, 8192);
    // 6. part[z] = P[:, z-chunk] @ Wh[z-chunk, :]  (BM=128 BN=256, z=4)
    k_gemm3<<<dim3(2, 64, 4), 512, 0, stream>>>(S, WhT, part);
    // 7. outf = sum(part) + X, fused column stats (256 blocks)
    k_reduce_stats<<<dim3(256), 256, 0, stream>>>(part, X, outf, cs, cq);
    // 8. batchnorm + leaky relu
    k_bn_lrelu<<<dim3((8192 * 512) / 256), 256, 0, stream>>>(outf, cs, cq, out);
}

// Round 7
// 544.835 us; speedup vs baseline: 1.1821x; 1.0386x over previous
//
#include <hip/hip_runtime.h>

using f32x4 = float    __attribute__((ext_vector_type(4)));
using f16x8 = _Float16 __attribute__((ext_vector_type(8)));
using f16x4 = _Float16 __attribute__((ext_vector_type(4)));

__device__ __forceinline__ void gload_lds16(const void* g, void* l) {
    __builtin_amdgcn_global_load_lds(
        (__attribute__((address_space(1))) void*)(void*)g,
        (__attribute__((address_space(3))) void*)l, 16, 0, 0);
}

// LDS k-seg swizzle (validated R3/R6): staging lane (seg=lane&3, row r16=lane>>2)
// pulls source k-seg ((seg-(r16>>1))&3); reader of k-seg `quad` for row lrow
// reads slot ((quad+(lrow>>1))&3). Bank aliasing collapses 8-way -> 2-way (free).

// ---------------- fp32 -> fp16 elementwise convert (8 elems/thread) ---------
__global__ __launch_bounds__(256) void k_cvt_x(
    const float* __restrict__ in, _Float16* __restrict__ out) {
    int i = (blockIdx.x * 256 + threadIdx.x) * 8;
    f32x4 a = *(const f32x4*)(in + i);
    f32x4 b = *(const f32x4*)(in + i + 4);
    f16x8 o;
    #pragma unroll
    for (int j = 0; j < 4; ++j) { o[j] = (_Float16)a[j]; o[j + 4] = (_Float16)b[j]; }
    *(f16x8*)(out + i) = o;
}

// ---------------- fp32 in [R][C] -> fp16 out[c][r] (convert + transpose) ----
__global__ __launch_bounds__(256) void k_cvtT(
    const float* __restrict__ in, _Float16* __restrict__ out, int R, int C) {
    __shared__ _Float16 tile[32][33];
    int c0 = blockIdx.x * 32, r0 = blockIdx.y * 32;
    int tx = threadIdx.x & 31, ty = threadIdx.x >> 5;
    #pragma unroll
    for (int i = ty; i < 32; i += 8)
        tile[i][tx] = (_Float16)in[(size_t)(r0 + i) * C + c0 + tx];
    __syncthreads();
    #pragma unroll
    for (int i = ty; i < 32; i += 8)
        out[(size_t)(c0 + i) * R + r0 + tx] = tile[tx][i];
}

// ------- fused GEMM1: Wh/Ws pair + tanh + transposed Wh output --------------
// grid (8,64), 512 thr / 8 waves (wm 0..1, wn 0..3). BM=128, 64 cols per half.
// A=Xh[8192,512], Bt=Wt[1024,512]; per block computes cols [c0,c0+64) of Wh
// (features col0..) and Ws (features col0+512..), then T=tanh(Wh+Ws+bias).
// Outputs: Whh, T fp16 [8192,512]; WhT fp16 [512,8192] (via f16x4 row-packs).
__global__ __launch_bounds__(512, 4) void k_gemm1f(
    const _Float16* __restrict__ A, const _Float16* __restrict__ Bt,
    _Float16* __restrict__ Whh, _Float16* __restrict__ T,
    _Float16* __restrict__ WhT,
    const float* __restrict__ aw, const float* __restrict__ ab) {
    __shared__ _Float16 As[128 * 32];
    __shared__ _Float16 B0s[64 * 32];
    __shared__ _Float16 B1s[64 * 32];
    const float bias = aw[0] + ab[0];
    const int row0 = blockIdx.y * 128, col0 = blockIdx.x * 64;
    const int tid = threadIdx.x, w = tid >> 6, lane = tid & 63;
    const int wm = w >> 2, wn = w & 3;
    const int lrow = lane & 15, quad = lane >> 4;
    const int r16 = lane >> 2;
    const int kc = (((lane & 3) - ((lane >> 3) & 3)) & 3) * 8;
    const int sq = ((quad + ((lrow >> 1) & 3)) & 3) * 8;
    f32x4 acc0[4] = {}, acc1[4] = {};
    for (int k0 = 0; k0 < 512; k0 += 32) {
        // 16 chunks (8 A + 4 B0 + 4 B1) / 8 waves = 2 each
        gload_lds16(A + (size_t)(row0 + w * 16 + r16) * 512 + k0 + kc,
                    As + w * 512);
        if (w < 4)
            gload_lds16(Bt + (size_t)(col0 + w * 16 + r16) * 512 + k0 + kc,
                        B0s + w * 512);
        else
            gload_lds16(Bt + (size_t)(col0 + 512 + (w - 4) * 16 + r16) * 512 + k0 + kc,
                        B1s + (w - 4) * 512);
        __syncthreads();
        f16x8 af[4], b0, b1;
        #pragma unroll
        for (int i = 0; i < 4; ++i)
            af[i] = *(const f16x8*)(As + (wm * 64 + i * 16 + lrow) * 32 + sq);
        b0 = *(const f16x8*)(B0s + (wn * 16 + lrow) * 32 + sq);
        b1 = *(const f16x8*)(B1s + (wn * 16 + lrow) * 32 + sq);
        #pragma unroll
        for (int mi = 0; mi < 4; ++mi) {
            acc0[mi] = __builtin_amdgcn_mfma_f32_16x16x32_f16(af[mi], b0, acc0[mi], 0, 0, 0);
            acc1[mi] = __builtin_amdgcn_mfma_f32_16x16x32_f16(af[mi], b1, acc1[mi], 0, 0, 0);
        }
        __syncthreads();
    }
    const int col = col0 + wn * 16 + lrow;
    #pragma unroll
    for (int mi = 0; mi < 4; ++mi) {
        int rowb = row0 + wm * 64 + mi * 16 + quad * 4;
        f16x4 pw;
        #pragma unroll
        for (int r = 0; r < 4; ++r) {
            float wh = acc0[mi][r];
            float tt = tanhf(wh + acc1[mi][r] + bias);
            Whh[(size_t)(rowb + r) * 512 + col] = (_Float16)wh;
            T[(size_t)(rowb + r) * 512 + col]   = (_Float16)tt;
            pw[r] = (_Float16)wh;
        }
        *(f16x4*)(WhT + (size_t)col * 8192 + rowb) = pw;
    }
}

// ---------------- GEMM2: S = T @ Whh^T  (BM=256, BN=128, 512 thr) -----------
// Wave grid 4x2 (wm 0..3, wn 0..1): wave = 64 rows x 64 cols. 24 chunks / 8
// waves = 3 gloads each; per-barrier block MFMA doubles vs 128^2 tile.
// grid (64,32) = 2048 blocks, 2 blocks/CU (reg structure == validated k_gemm3).
__global__ __launch_bounds__(512, 4) void k_gemm2(
    const _Float16* __restrict__ A,      // T [8192,512]
    const _Float16* __restrict__ Bt,     // Whh [8192,512]
    _Float16* __restrict__ Cp) {         // S [8192,8192]
    __shared__ _Float16 As[256 * 32];
    __shared__ _Float16 Bs[128 * 32];
    const int row0 = blockIdx.y * 256, col0 = blockIdx.x * 128;
    const int tid = threadIdx.x, w = tid >> 6, lane = tid & 63;
    const int wm = w >> 1, wn = w & 1;
    const int lrow = lane & 15, quad = lane >> 4;
    const int r16 = lane >> 2;
    const int kc = (((lane & 3) - ((lane >> 3) & 3)) & 3) * 8;
    const int sq = ((quad + ((lrow >> 1) & 3)) & 3) * 8;
    f32x4 acc[4][4] = {};
    for (int k0 = 0; k0 < 512; k0 += 32) {
        #pragma unroll
        for (int i = 0; i < 3; ++i) {
            int c = w + i * 8;           // 24 chunks
            if (c < 16) {
                gload_lds16(A + (size_t)(row0 + c * 16 + r16) * 512 + k0 + kc,
                            As + c * 512);
            } else {
                int c2 = c - 16;
                gload_lds16(Bt + (size_t)(col0 + c2 * 16 + r16) * 512 + k0 + kc,
                            Bs + c2 * 512);
            }
        }
        __syncthreads();
        f16x8 af[4], bf[4];
        #pragma unroll
        for (int i = 0; i < 4; ++i)
            af[i] = *(const f16x8*)(As + (wm * 64 + i * 16 + lrow) * 32 + sq);
        #pragma unroll
        for (int i = 0; i < 4; ++i)
            bf[i] = *(const f16x8*)(Bs + (wn * 64 + i * 16 + lrow) * 32 + sq);
        #pragma unroll
        for (int mi = 0; mi < 4; ++mi)
            #pragma unroll
            for (int ni = 0; ni < 4; ++ni)
                acc[mi][ni] = __builtin_amdgcn_mfma_f32_16x16x32_f16(
                    af[mi], bf[ni], acc[mi][ni], 0, 0, 0);
        __syncthreads();
    }
    #pragma unroll
    for (int mi = 0; mi < 4; ++mi) {
        #pragma unroll
        for (int ni = 0; ni < 4; ++ni) {
            int col = col0 + wn * 64 + ni * 16 + lrow;
            #pragma unroll
            for (int r = 0; r < 4; ++r) {
                int row = row0 + wm * 64 + mi * 16 + quad * 4 + r;
                Cp[(size_t)row * 8192 + col] = (_Float16)acc[mi][ni][r];
            }
        }
    }
}

// ------- GEMM3: part[z] = P[:, zchunk] @ Wh[zchunk, :]  (R6-validated) ------
__global__ __launch_bounds__(512, 4) void k_gemm3(
    const _Float16* __restrict__ A,      // P [8192][8192]
    const _Float16* __restrict__ Bt,     // WhT [512][8192]
    float* __restrict__ Cp) {            // partials [4][8192][512]
    __shared__ _Float16 As[128 * 32];
    __shared__ _Float16 Bs[256 * 32];
    const int row0 = blockIdx.y * 128, col0 = blockIdx.x * 256;
    const size_t zoff = (size_t)blockIdx.z * 2048;
    Cp += (size_t)blockIdx.z * ((size_t)8192 * 512);
    const int tid = threadIdx.x, w = tid >> 6, lane = tid & 63;
    const int wm = w >> 2, wn = w & 3;
    const int lrow = lane & 15, quad = lane >> 4;
    const int r16 = lane >> 2;
    const int kc = (((lane & 3) - ((lane >> 3) & 3)) & 3) * 8;
    const int sq = ((quad + ((lrow >> 1) & 3)) & 3) * 8;
    f32x4 acc[4][4] = {};
    for (int k0 = 0; k0 < 2048; k0 += 32) {
        #pragma unroll
        for (int i = 0; i < 3; ++i) {
            int c = w + i * 8;           // 24 chunks / 8 waves
            if (c < 8) {
                gload_lds16(A + (size_t)(row0 + c * 16 + r16) * 8192 + zoff + k0 + kc,
                            As + c * 512);
            } else {
                int c2 = c - 8;
                gload_lds16(Bt + (size_t)(col0 + c2 * 16 + r16) * 8192 + zoff + k0 + kc,
                            Bs + c2 * 512);
            }
        }
        __syncthreads();
        f16x8 af[4], bf[4];
        #pragma unroll
        for (int i = 0; i < 4; ++i)
            af[i] = *(const f16x8*)(As + (wm * 64 + i * 16 + lrow) * 32 + sq);
        #pragma unroll
        for (int i = 0; i < 4; ++i)
            bf[i] = *(const f16x8*)(Bs + (wn * 64 + i * 16 + lrow) * 32 + sq);
        #pragma unroll
        for (int mi = 0; mi < 4; ++mi)
            #pragma unroll
            for (int ni = 0; ni < 4; ++ni)
                acc[mi][ni] = __builtin_amdgcn_mfma_f32_16x16x32_f16(
                    af[mi], bf[ni], acc[mi][ni], 0, 0, 0);
        __syncthreads();
    }
    #pragma unroll
    for (int mi = 0; mi < 4; ++mi) {
        #pragma unroll
        for (int ni = 0; ni < 4; ++ni) {
            int col = col0 + wn * 64 + ni * 16 + lrow;
            #pragma unroll
            for (int r = 0; r < 4; ++r) {
                int row = row0 + wm * 64 + mi * 16 + quad * 4 + r;
                Cp[(size_t)row * 512 + col] = acc[mi][ni][r];
            }
        }
    }
}

// ---------------- row softmax in place: S fp16 -> P fp16 --------------------
__global__ __launch_bounds__(256) void k_softmax_rows(
    _Float16* __restrict__ S, int N) {
    const int row = blockIdx.x;
    _Float16* prow = S + (size_t)row * N;
    const int t = threadIdx.x;
    float v[32];
    #pragma unroll
    for (int it = 0; it < 4; ++it) {
        f16x8 h = *(const f16x8*)(prow + (it * 256 + t) * 8);
        #pragma unroll
        for (int j = 0; j < 8; ++j) v[it * 8 + j] = (float)h[j];
    }
    float m = v[0];
    #pragma unroll
    for (int j = 1; j < 32; ++j) m = fmaxf(m, v[j]);
    #pragma unroll
    for (int off = 32; off > 0; off >>= 1) m = fmaxf(m, __shfl_xor(m, off));
    __shared__ float red[8];
    const int wid = t >> 6, lane = t & 63;
    if (lane == 0) red[wid] = m;
    __syncthreads();
    m = fmaxf(fmaxf(red[0], red[1]), fmaxf(red[2], red[3]));
    float l = 0.f;
    #pragma unroll
    for (int j = 0; j < 32; ++j) { v[j] = __expf(v[j] - m); l += v[j]; }
    #pragma unroll
    for (int off = 32; off > 0; off >>= 1) l += __shfl_xor(l, off);
    if (lane == 0) red[4 + wid] = l;
    __syncthreads();
    float rl = 1.f / (red[4] + red[5] + red[6] + red[7]);
    #pragma unroll
    for (int it = 0; it < 4; ++it) {
        f16x8 pk;
        #pragma unroll
        for (int j = 0; j < 8; ++j)
            pk[j] = (_Float16)(v[it * 8 + j] * rl);
        *(f16x8*)(prow + (it * 256 + t) * 8) = pk;
    }
}

// ------- fused: outf = sum(part[0..3]) + X, plus column sum/sumsq atomics ---
__global__ __launch_bounds__(256) void k_reduce_stats(
    const float* __restrict__ part, const float* __restrict__ X,
    float* __restrict__ outf, float* __restrict__ cs, float* __restrict__ cq) {
    const int t = threadIdx.x;
    const int r0 = blockIdx.x * 32;
    constexpr size_t PS = (size_t)8192 * 512;
    float s0 = 0, q0 = 0, s1 = 0, q1 = 0;
    for (int r = 0; r < 32; ++r) {
        size_t base = (size_t)(r0 + r) * 512;
        float a = part[base + t] + part[PS + base + t]
                + part[2 * PS + base + t] + part[3 * PS + base + t] + X[base + t];
        float b = part[base + t + 256] + part[PS + base + t + 256]
                + part[2 * PS + base + t + 256] + part[3 * PS + base + t + 256]
                + X[base + t + 256];
        outf[base + t] = a;       outf[base + t + 256] = b;
        s0 += a; q0 += a * a; s1 += b; q1 += b * b;
    }
    atomicAdd(&cs[t], s0);       atomicAdd(&cq[t], q0);
    atomicAdd(&cs[t + 256], s1); atomicAdd(&cq[t + 256], q1);
}

// ---------------- batchnorm (no affine) + leaky relu -> fp32 ----------------
__global__ __launch_bounds__(256) void k_bn_lrelu(
    const float* __restrict__ outf, const float* __restrict__ colsum,
    const float* __restrict__ colsq, float* __restrict__ out) {
    int i = blockIdx.x * 256 + threadIdx.x;
    int c = i & 511;
    constexpr float rN = 1.f / 8192.f;
    float mean = colsum[c] * rN;
    float var  = colsq[c] * rN - mean * mean;
    float y = (outf[i] - mean) * rsqrtf(var + 1e-5f);
    y = (y >= 0.f) ? y : 0.01f * y;
    out[i] = y;
}

extern "C" void kernel_launch(void* const* d_in, const int* in_sizes, int n_in,
                              void* d_out, int out_size, void* d_ws, size_t ws_size,
                              hipStream_t stream) {
    const float* X  = (const float*)d_in[0];  // [8192,512] fp32
    // d_in[1] = adj, unused
    const float* W  = (const float*)d_in[2];  // [512,1024] fp32
    const float* aw = (const float*)d_in[3];
    const float* ab = (const float*)d_in[4];
    float* out = (float*)d_out;               // [8192,512] fp32

    char* ws = (char*)d_ws;
    _Float16* Xh   = (_Float16*)(ws + 0x0);          //   8 MB [8192,512]
    _Float16* Wt   = (_Float16*)(ws + 0x800000);     //   1 MB W^T [1024,512]
    _Float16* T    = (_Float16*)(ws + 0x900000);     //   8 MB [8192,512]
    _Float16* Whh  = (_Float16*)(ws + 0x1100000);    //   8 MB [8192,512]
    _Float16* WhT  = (_Float16*)(ws + 0x1900000);    //   8 MB [512,8192]
    _Float16* S    = (_Float16*)(ws + 0x2100000);    // 128 MB [8192,8192] fp16
    float*    outf = (float*)   (ws + 0xA100000);    //  16 MB [8192,512] fp32
    float*    part = (float*)   (ws + 0xB100000);    //  64 MB 4x[8192,512] fp32
    float*    cs   = (float*)   (ws + 0xF100000);    //   2 KB
    float*    cq   = (float*)   (ws + 0xF100800);    //   2 KB

    // stats accumulators zeroed up-front
    hipMemsetAsync(cs, 0, 4096, stream);
    // 0. Xh = fp16(X);  Wt = fp16(W^T)
    k_cvt_x<<<dim3((8192 * 512) / 2048), 256, 0, stream>>>(X, Xh);
    k_cvtT<<<dim3(1024 / 32, 512 / 32), 256, 0, stream>>>(W, Wt, 512, 1024);
    // 1. fused: Whh/T/WhT from Xh @ Wt (both halves + tanh + transpose)
    k_gemm1f<<<dim3(8, 64), 512, 0, stream>>>(Xh, Wt, Whh, T, WhT, aw, ab);
    // 2. S = T @ Whh^T  (fp16)  M=8192 N=8192 K=512, 256x128 tile
    k_gemm2<<<dim3(64, 32), 512, 0, stream>>>(T, Whh, S);
    // 3. row softmax in place: S -> P (fp16)
    k_softmax_rows<<<dim3(8192), 256, 0, stream>>>(S, 8192);
    // 4. part[z] = P[:, z-chunk] @ Wh[z-chunk, :]  (BM=128 BN=256, z=4)
    k_gemm3<<<dim3(2, 64, 4), 512, 0, stream>>>(S, WhT, part);
    // 5. outf = sum(part) + X, fused column stats (256 blocks)
    k_reduce_stats<<<dim3(256), 256, 0, stream>>>(part, X, outf, cs, cq);
    // 6. batchnorm + leaky relu
    k_bn_lrelu<<<dim3((8192 * 512) / 256), 256, 0, stream>>>(outf, cs, cq, out);
}

// Round 8
// 509.722 us; speedup vs baseline: 1.2636x; 1.0689x over previous
//
#include <hip/hip_runtime.h>

using f32x4 = float    __attribute__((ext_vector_type(4)));
using f16x8 = _Float16 __attribute__((ext_vector_type(8)));
using f16x4 = _Float16 __attribute__((ext_vector_type(4)));

__device__ __forceinline__ void gload_lds16(const void* g, void* l) {
    __builtin_amdgcn_global_load_lds(
        (__attribute__((address_space(1))) void*)(void*)g,
        (__attribute__((address_space(3))) void*)l, 16, 0, 0);
}

// BK=32 swizzle (validated R3/R6/R7), rows 64B apart, 4 slots of 16B:
//   stage: lane seg=lane&3 row r16=lane>>2 pulls k-seg ((seg-(r16>>1))&3)
//   read:  k-seg `quad` of row lrow at slot ((quad+(lrow>>1))&3)
// BK=64 swizzle (new): rows 128B apart, 8 slots of 16B, rotate by row:
//   stage: lane seg=lane&7 row r8=lane>>3 pulls k-seg ((seg-r8)&7)
//   read:  k-seg (quad+4*ks) of row lrow at slot ((quad+4*ks+lrow)&7)
// Each 8-lane phase of ds_read_b128 covers all 32 banks exactly once.

// ---------------- fp32 -> fp16 elementwise convert (8 elems/thread) ---------
__global__ __launch_bounds__(256) void k_cvt_x(
    const float* __restrict__ in, _Float16* __restrict__ out) {
    int i = (blockIdx.x * 256 + threadIdx.x) * 8;
    f32x4 a = *(const f32x4*)(in + i);
    f32x4 b = *(const f32x4*)(in + i + 4);
    f16x8 o;
    #pragma unroll
    for (int j = 0; j < 4; ++j) { o[j] = (_Float16)a[j]; o[j + 4] = (_Float16)b[j]; }
    *(f16x8*)(out + i) = o;
}

// ---------------- fp32 in [R][C] -> fp16 out[c][r] (convert + transpose) ----
__global__ __launch_bounds__(256) void k_cvtT(
    const float* __restrict__ in, _Float16* __restrict__ out, int R, int C) {
    __shared__ _Float16 tile[32][33];
    int c0 = blockIdx.x * 32, r0 = blockIdx.y * 32;
    int tx = threadIdx.x & 31, ty = threadIdx.x >> 5;
    #pragma unroll
    for (int i = ty; i < 32; i += 8)
        tile[i][tx] = (_Float16)in[(size_t)(r0 + i) * C + c0 + tx];
    __syncthreads();
    #pragma unroll
    for (int i = ty; i < 32; i += 8)
        out[(size_t)(c0 + i) * R + r0 + tx] = tile[tx][i];
}

// ------- fused GEMM1: Wh/Ws pair + tanh + transposed Wh output (R7-valid) ---
__global__ __launch_bounds__(512, 4) void k_gemm1f(
    const _Float16* __restrict__ A, const _Float16* __restrict__ Bt,
    _Float16* __restrict__ Whh, _Float16* __restrict__ T,
    _Float16* __restrict__ WhT,
    const float* __restrict__ aw, const float* __restrict__ ab) {
    __shared__ _Float16 As[128 * 32];
    __shared__ _Float16 B0s[64 * 32];
    __shared__ _Float16 B1s[64 * 32];
    const float bias = aw[0] + ab[0];
    const int row0 = blockIdx.y * 128, col0 = blockIdx.x * 64;
    const int tid = threadIdx.x, w = tid >> 6, lane = tid & 63;
    const int wm = w >> 2, wn = w & 3;
    const int lrow = lane & 15, quad = lane >> 4;
    const int r16 = lane >> 2;
    const int kc = (((lane & 3) - ((lane >> 3) & 3)) & 3) * 8;
    const int sq = ((quad + ((lrow >> 1) & 3)) & 3) * 8;
    f32x4 acc0[4] = {}, acc1[4] = {};
    for (int k0 = 0; k0 < 512; k0 += 32) {
        gload_lds16(A + (size_t)(row0 + w * 16 + r16) * 512 + k0 + kc,
                    As + w * 512);
        if (w < 4)
            gload_lds16(Bt + (size_t)(col0 + w * 16 + r16) * 512 + k0 + kc,
                        B0s + w * 512);
        else
            gload_lds16(Bt + (size_t)(col0 + 512 + (w - 4) * 16 + r16) * 512 + k0 + kc,
                        B1s + (w - 4) * 512);
        __syncthreads();
        f16x8 af[4], b0, b1;
        #pragma unroll
        for (int i = 0; i < 4; ++i)
            af[i] = *(const f16x8*)(As + (wm * 64 + i * 16 + lrow) * 32 + sq);
        b0 = *(const f16x8*)(B0s + (wn * 16 + lrow) * 32 + sq);
        b1 = *(const f16x8*)(B1s + (wn * 16 + lrow) * 32 + sq);
        #pragma unroll
        for (int mi = 0; mi < 4; ++mi) {
            acc0[mi] = __builtin_amdgcn_mfma_f32_16x16x32_f16(af[mi], b0, acc0[mi], 0, 0, 0);
            acc1[mi] = __builtin_amdgcn_mfma_f32_16x16x32_f16(af[mi], b1, acc1[mi], 0, 0, 0);
        }
        __syncthreads();
    }
    const int col = col0 + wn * 16 + lrow;
    #pragma unroll
    for (int mi = 0; mi < 4; ++mi) {
        int rowb = row0 + wm * 64 + mi * 16 + quad * 4;
        f16x4 pw;
        #pragma unroll
        for (int r = 0; r < 4; ++r) {
            float wh = acc0[mi][r];
            float tt = tanhf(wh + acc1[mi][r] + bias);
            Whh[(size_t)(rowb + r) * 512 + col] = (_Float16)wh;
            T[(size_t)(rowb + r) * 512 + col]   = (_Float16)tt;
            pw[r] = (_Float16)wh;
        }
        *(f16x4*)(WhT + (size_t)col * 8192 + rowb) = pw;
    }
}

// ---------------- GEMM2: S = T @ Whh^T  (BM=256, BN=128, BK=64) -------------
// 512 thr / 8 waves (4x2). 48 staging chunks (8 rows x 128B each) / 8 waves
// = 6 gloads per wave per 64-k iter; ONE barrier per 64-k (halved drains).
// LDS 48KB -> 2 blocks/CU. grid (64,32) = 2048 blocks.
__global__ __launch_bounds__(512, 4) void k_gemm2(
    const _Float16* __restrict__ A,      // T [8192,512]
    const _Float16* __restrict__ Bt,     // Whh [8192,512]
    _Float16* __restrict__ Cp) {         // S [8192,8192]
    __shared__ _Float16 As[256 * 64];
    __shared__ _Float16 Bs[128 * 64];
    const int row0 = blockIdx.y * 256, col0 = blockIdx.x * 128;
    const int tid = threadIdx.x, w = tid >> 6, lane = tid & 63;
    const int wm = w >> 1, wn = w & 1;
    const int lrow = lane & 15, quad = lane >> 4;
    const int r8 = lane >> 3;                       // row within 8-row chunk
    const int kc8 = (((lane & 7) - r8) & 7) * 8;    // staged source k-seg
    f32x4 acc[4][4] = {};
    for (int k0 = 0; k0 < 512; k0 += 64) {
        #pragma unroll
        for (int i = 0; i < 6; ++i) {
            int c = w + i * 8;                      // 48 chunks
            if (c < 32) {
                gload_lds16(A + (size_t)(row0 + c * 8 + r8) * 512 + k0 + kc8,
                            As + c * 512);
            } else {
                int c2 = c - 32;
                gload_lds16(Bt + (size_t)(col0 + c2 * 8 + r8) * 512 + k0 + kc8,
                            Bs + c2 * 512);
            }
        }
        __syncthreads();
        #pragma unroll
        for (int ks = 0; ks < 2; ++ks) {
            const int sl = ((quad + ks * 4 + lrow) & 7) * 8;
            f16x8 af[4], bf[4];
            #pragma unroll
            for (int i = 0; i < 4; ++i)
                af[i] = *(const f16x8*)(As + (wm * 64 + i * 16 + lrow) * 64 + sl);
            #pragma unroll
            for (int i = 0; i < 4; ++i)
                bf[i] = *(const f16x8*)(Bs + (wn * 64 + i * 16 + lrow) * 64 + sl);
            #pragma unroll
            for (int mi = 0; mi < 4; ++mi)
                #pragma unroll
                for (int ni = 0; ni < 4; ++ni)
                    acc[mi][ni] = __builtin_amdgcn_mfma_f32_16x16x32_f16(
                        af[mi], bf[ni], acc[mi][ni], 0, 0, 0);
        }
        __syncthreads();
    }
    #pragma unroll
    for (int mi = 0; mi < 4; ++mi) {
        #pragma unroll
        for (int ni = 0; ni < 4; ++ni) {
            int col = col0 + wn * 64 + ni * 16 + lrow;
            #pragma unroll
            for (int r = 0; r < 4; ++r) {
                int row = row0 + wm * 64 + mi * 16 + quad * 4 + r;
                Cp[(size_t)row * 8192 + col] = (_Float16)acc[mi][ni][r];
            }
        }
    }
}

// ------- GEMM3: part[z] = P[:, zchunk] @ Wh[zchunk, :]  (BK=64, z=4) --------
// BM=128, BN=256, 512 thr / 8 waves (2x4). 48 chunks / 8 waves = 6 gloads;
// one barrier per 64-k (32 vs 64 drains). LDS 48KB, grid (2,64,4)=512 blocks.
__global__ __launch_bounds__(512, 4) void k_gemm3(
    const _Float16* __restrict__ A,      // P [8192][8192]
    const _Float16* __restrict__ Bt,     // WhT [512][8192]
    float* __restrict__ Cp) {            // partials [4][8192][512]
    __shared__ _Float16 As[128 * 64];
    __shared__ _Float16 Bs[256 * 64];
    const int row0 = blockIdx.y * 128, col0 = blockIdx.x * 256;
    const size_t zoff = (size_t)blockIdx.z * 2048;
    Cp += (size_t)blockIdx.z * ((size_t)8192 * 512);
    const int tid = threadIdx.x, w = tid >> 6, lane = tid & 63;
    const int wm = w >> 2, wn = w & 3;
    const int lrow = lane & 15, quad = lane >> 4;
    const int r8 = lane >> 3;
    const int kc8 = (((lane & 7) - r8) & 7) * 8;
    f32x4 acc[4][4] = {};
    for (int k0 = 0; k0 < 2048; k0 += 64) {
        #pragma unroll
        for (int i = 0; i < 6; ++i) {
            int c = w + i * 8;                      // 48 chunks (16 A + 32 B)
            if (c < 16) {
                gload_lds16(A + (size_t)(row0 + c * 8 + r8) * 8192 + zoff + k0 + kc8,
                            As + c * 512);
            } else {
                int c2 = c - 16;
                gload_lds16(Bt + (size_t)(col0 + c2 * 8 + r8) * 8192 + zoff + k0 + kc8,
                            Bs + c2 * 512);
            }
        }
        __syncthreads();
        #pragma unroll
        for (int ks = 0; ks < 2; ++ks) {
            const int sl = ((quad + ks * 4 + lrow) & 7) * 8;
            f16x8 af[4], bf[4];
            #pragma unroll
            for (int i = 0; i < 4; ++i)
                af[i] = *(const f16x8*)(As + (wm * 64 + i * 16 + lrow) * 64 + sl);
            #pragma unroll
            for (int i = 0; i < 4; ++i)
                bf[i] = *(const f16x8*)(Bs + (wn * 64 + i * 16 + lrow) * 64 + sl);
            #pragma unroll
            for (int mi = 0; mi < 4; ++mi)
                #pragma unroll
                for (int ni = 0; ni < 4; ++ni)
                    acc[mi][ni] = __builtin_amdgcn_mfma_f32_16x16x32_f16(
                        af[mi], bf[ni], acc[mi][ni], 0, 0, 0);
        }
        __syncthreads();
    }
    #pragma unroll
    for (int mi = 0; mi < 4; ++mi) {
        #pragma unroll
        for (int ni = 0; ni < 4; ++ni) {
            int col = col0 + wn * 64 + ni * 16 + lrow;
            #pragma unroll
            for (int r = 0; r < 4; ++r) {
                int row = row0 + wm * 64 + mi * 16 + quad * 4 + r;
                Cp[(size_t)row * 512 + col] = acc[mi][ni][r];
            }
        }
    }
}

// ---------------- row softmax in place: S fp16 -> P fp16 --------------------
__global__ __launch_bounds__(256) void k_softmax_rows(
    _Float16* __restrict__ S, int N) {
    const int row = blockIdx.x;
    _Float16* prow = S + (size_t)row * N;
    const int t = threadIdx.x;
    float v[32];
    #pragma unroll
    for (int it = 0; it < 4; ++it) {
        f16x8 h = *(const f16x8*)(prow + (it * 256 + t) * 8);
        #pragma unroll
        for (int j = 0; j < 8; ++j) v[it * 8 + j] = (float)h[j];
    }
    float m = v[0];
    #pragma unroll
    for (int j = 1; j < 32; ++j) m = fmaxf(m, v[j]);
    #pragma unroll
    for (int off = 32; off > 0; off >>= 1) m = fmaxf(m, __shfl_xor(m, off));
    __shared__ float red[8];
    const int wid = t >> 6, lane = t & 63;
    if (lane == 0) red[wid] = m;
    __syncthreads();
    m = fmaxf(fmaxf(red[0], red[1]), fmaxf(red[2], red[3]));
    float l = 0.f;
    #pragma unroll
    for (int j = 0; j < 32; ++j) { v[j] = __expf(v[j] - m); l += v[j]; }
    #pragma unroll
    for (int off = 32; off > 0; off >>= 1) l += __shfl_xor(l, off);
    if (lane == 0) red[4 + wid] = l;
    __syncthreads();
    float rl = 1.f / (red[4] + red[5] + red[6] + red[7]);
    #pragma unroll
    for (int it = 0; it < 4; ++it) {
        f16x8 pk;
        #pragma unroll
        for (int j = 0; j < 8; ++j)
            pk[j] = (_Float16)(v[it * 8 + j] * rl);
        *(f16x8*)(prow + (it * 256 + t) * 8) = pk;
    }
}

// ------- fused: outf = sum(part[0..3]) + X, plus column sum/sumsq atomics ---
__global__ __launch_bounds__(256) void k_reduce_stats(
    const float* __restrict__ part, const float* __restrict__ X,
    float* __restrict__ outf, float* __restrict__ cs, float* __restrict__ cq) {
    const int t = threadIdx.x;
    const int r0 = blockIdx.x * 32;
    constexpr size_t PS = (size_t)8192 * 512;
    float s0 = 0, q0 = 0, s1 = 0, q1 = 0;
    for (int r = 0; r < 32; ++r) {
        size_t base = (size_t)(r0 + r) * 512;
        float a = part[base + t] + part[PS + base + t]
                + part[2 * PS + base + t] + part[3 * PS + base + t] + X[base + t];
        float b = part[base + t + 256] + part[PS + base + t + 256]
                + part[2 * PS + base + t + 256] + part[3 * PS + base + t + 256]
                + X[base + t + 256];
        outf[base + t] = a;       outf[base + t + 256] = b;
        s0 += a; q0 += a * a; s1 += b; q1 += b * b;
    }
    atomicAdd(&cs[t], s0);       atomicAdd(&cq[t], q0);
    atomicAdd(&cs[t + 256], s1); atomicAdd(&cq[t + 256], q1);
}

// ---------------- batchnorm (no affine) + leaky relu -> fp32 ----------------
__global__ __launch_bounds__(256) void k_bn_lrelu(
    const float* __restrict__ outf, const float* __restrict__ colsum,
    const float* __restrict__ colsq, float* __restrict__ out) {
    int i = blockIdx.x * 256 + threadIdx.x;
    int c = i & 511;
    constexpr float rN = 1.f / 8192.f;
    float mean = colsum[c] * rN;
    float var  = colsq[c] * rN - mean * mean;
    float y = (outf[i] - mean) * rsqrtf(var + 1e-5f);
    y = (y >= 0.f) ? y : 0.01f * y;
    out[i] = y;
}

extern "C" void kernel_launch(void* const* d_in, const int* in_sizes, int n_in,
                              void* d_out, int out_size, void* d_ws, size_t ws_size,
                              hipStream_t stream) {
    const float* X  = (const float*)d_in[0];  // [8192,512] fp32
    // d_in[1] = adj, unused
    const float* W  = (const float*)d_in[2];  // [512,1024] fp32
    const float* aw = (const float*)d_in[3];
    const float* ab = (const float*)d_in[4];
    float* out = (float*)d_out;               // [8192,512] fp32

    char* ws = (char*)d_ws;
    _Float16* Xh   = (_Float16*)(ws + 0x0);          //   8 MB [8192,512]
    _Float16* Wt   = (_Float16*)(ws + 0x800000);     //   1 MB W^T [1024,512]
    _Float16* T    = (_Float16*)(ws + 0x900000);     //   8 MB [8192,512]
    _Float16* Whh  = (_Float16*)(ws + 0x1100000);    //   8 MB [8192,512]
    _Float16* WhT  = (_Float16*)(ws + 0x1900000);    //   8 MB [512,8192]
    _Float16* S    = (_Float16*)(ws + 0x2100000);    // 128 MB [8192,8192] fp16
    float*    outf = (float*)   (ws + 0xA100000);    //  16 MB [8192,512] fp32
    float*    part = (float*)   (ws + 0xB100000);    //  64 MB 4x[8192,512] fp32
    float*    cs   = (float*)   (ws + 0xF100000);    //   2 KB
    float*    cq   = (float*)   (ws + 0xF100800);    //   2 KB

    // stats accumulators zeroed up-front
    hipMemsetAsync(cs, 0, 4096, stream);
    // 0. Xh = fp16(X);  Wt = fp16(W^T)
    k_cvt_x<<<dim3((8192 * 512) / 2048), 256, 0, stream>>>(X, Xh);
    k_cvtT<<<dim3(1024 / 32, 512 / 32), 256, 0, stream>>>(W, Wt, 512, 1024);
    // 1. fused: Whh/T/WhT from Xh @ Wt (both halves + tanh + transpose)
    k_gemm1f<<<dim3(8, 64), 512, 0, stream>>>(Xh, Wt, Whh, T, WhT, aw, ab);
    // 2. S = T @ Whh^T  (fp16)  M=8192 N=8192 K=512, 256x128 tile, BK=64
    k_gemm2<<<dim3(64, 32), 512, 0, stream>>>(T, Whh, S);
    // 3. row softmax in place: S -> P (fp16)
    k_softmax_rows<<<dim3(8192), 256, 0, stream>>>(S, 8192);
    // 4. part[z] = P[:, z-chunk] @ Wh[z-chunk, :]  (BM=128 BN=256, BK=64, z=4)
    k_gemm3<<<dim3(2, 64, 4), 512, 0, stream>>>(S, WhT, part);
    // 5. outf = sum(part) + X, fused column stats (256 blocks)
    k_reduce_stats<<<dim3(256), 256, 0, stream>>>(part, X, outf, cs, cq);
    // 6. batchnorm + leaky relu
    k_bn_lrelu<<<dim3((8192 * 512) / 256), 256, 0, stream>>>(outf, cs, cq, out);
}